// Round 6
// baseline (421.451 us; speedup 1.0000x reference)
//
#include <hip/hip_runtime.h>
#include <math.h>

#define B_   4
#define N_   2048
#define DIM_ 1024
#define H_   16
#define DH_  64
#define M_   (B_ * N_)          // 8192
#define QKV_ELEMS ((size_t)B_ * H_ * N_ * DH_)   // 8388608

typedef __attribute__((ext_vector_type(8))) short short8;   // 8 bf16 (4 VGPRs)
typedef __attribute__((ext_vector_type(4))) float floatx4;  // MFMA C/D frag

// round-to-nearest-even float -> bf16 bits
static __device__ inline unsigned short f2bf(float f) {
    union { float f; unsigned u; } v; v.f = f;
    unsigned r = (v.u + 0x7fffu + ((v.u >> 16) & 1u)) >> 16;
    return (unsigned short)r;
}

// pack two f32 -> two bf16 (round-half-up)
static __device__ inline unsigned pkbf(float a, float b) {
    unsigned ua = (__float_as_uint(a) + 0x8000u) >> 16;
    unsigned ub = (__float_as_uint(b) + 0x8000u) & 0xffff0000u;
    return ua | ub;
}

// async global->LDS, 16 B per lane. lds dest = wave-uniform base + lane*16.
static __device__ inline void async_copy16(const void* g, void* l) {
    __builtin_amdgcn_global_load_lds(
        (const __attribute__((address_space(1))) unsigned int*)g,
        (__attribute__((address_space(3))) unsigned int*)l, 16, 0, 0);
}

// ---------------------------------------------------------------------------
// Kernel 0: fp32 -> bf16 convert
// ---------------------------------------------------------------------------
__global__ __launch_bounds__(256) void f32_to_bf16_kernel(
    const float* __restrict__ src, unsigned short* __restrict__ dst, int n8)
{
    int i = blockIdx.x * 256 + threadIdx.x;
    if (i >= n8) return;
    float4 a = ((const float4*)src)[i * 2];
    float4 b = ((const float4*)src)[i * 2 + 1];
    short8 o;
    o[0] = f2bf(a.x); o[1] = f2bf(a.y); o[2] = f2bf(a.z); o[3] = f2bf(a.w);
    o[4] = f2bf(b.x); o[5] = f2bf(b.y); o[6] = f2bf(b.z); o[7] = f2bf(b.w);
    *(short8*)(dst + (size_t)i * 8) = o;
}

// ---------------------------------------------------------------------------
// bf16 MFMA GEMM core v3: C[m,n] = sum_k A[m,k]*B[n,k]
//  Round-5 post-mortem: T2 killed conflicts (6.3M->0) but dur unchanged =
//  regime-gate (m252): at 2-phase the critical path is stage+vmcnt+barrier,
//  and 128^2/BK=32 gives only 16 MFMA per barrier. Fix = bigger tile at the
//  SAME sync structure (reference: 2ph large-tile @K=1024 measures 655-682
//  TF, m248/m230): BM=128 x BN=256, 4 waves (2Mx2N), per-wave 64x128 ->
//  32 MFMA : 12 ds_read : 6 stage-issues per K-step.
//   - issue-early double-buffer (kept), T2 both-sides swizzle (kept),
//     XCD-aware bijective block swizzle (added; A-panel L2 reuse per XCD).
// ---------------------------------------------------------------------------
#define GEMM_BODY(Aptr, Bptr, K, M0, N0)                                       \
    __shared__ unsigned short As[2][128 * 32];                                 \
    __shared__ unsigned short Bs[2][256 * 32];                                 \
    const int tid  = threadIdx.x;                                              \
    const int lane = tid & 63;                                                 \
    const int wv   = tid >> 6;                                                 \
    const int l15  = lane & 15, quad = lane >> 4;                              \
    const int wrow = (wv >> 1) * 64, wcol = (wv & 1) * 128;                    \
    const int m0 = (M0), n0 = (N0);                                            \
    const int lrow = lane >> 2;                                                \
    const int lkc  = (((lane & 3) ^ ((lane >> 3) & 3)) * 8); /* pre-swizzled */\
    const int srd  = (l15 >> 1) & 3;                    /* read-side swizzle */\
    const unsigned short* ga = Aptr + (size_t)(m0 + wv * 32 + lrow) * K + lkc; \
    const unsigned short* gb = Bptr + (size_t)(n0 + wv * 64 + lrow) * K + lkc; \
    floatx4 acc[4][8] = {};                                                    \
    _Pragma("unroll")                                                          \
    for (int c = 0; c < 2; ++c)                                                \
        async_copy16(ga + (size_t)c * 16 * K, &As[0][wv * 1024 + c * 512]);    \
    _Pragma("unroll")                                                          \
    for (int c = 0; c < 4; ++c)                                                \
        async_copy16(gb + (size_t)c * 16 * K, &Bs[0][wv * 2048 + c * 512]);    \
    for (int t = 0; t < (K) / 32; ++t) {                                       \
        const int cur = t & 1;                                                 \
        __syncthreads();           /* drains prev-issued loads: tile t ready */\
        if (t + 1 < (K) / 32) {                                                \
            const int k1 = (t + 1) * 32;                                       \
            _Pragma("unroll")                                                  \
            for (int c = 0; c < 2; ++c)                                        \
                async_copy16(ga + (size_t)c * 16 * K + k1,                     \
                             &As[cur ^ 1][wv * 1024 + c * 512]);               \
            _Pragma("unroll")                                                  \
            for (int c = 0; c < 4; ++c)                                        \
                async_copy16(gb + (size_t)c * 16 * K + k1,                     \
                             &Bs[cur ^ 1][wv * 2048 + c * 512]);               \
        }                                                                      \
        short8 af[4], bf[8];                                                   \
        _Pragma("unroll")                                                      \
        for (int mt = 0; mt < 4; ++mt)                                         \
            af[mt] = *(const short8*)&As[cur][(wrow + mt * 16 + l15) * 32 +    \
                                             ((quad ^ srd) * 8)];              \
        _Pragma("unroll")                                                      \
        for (int nt = 0; nt < 8; ++nt)                                         \
            bf[nt] = *(const short8*)&Bs[cur][(wcol + nt * 16 + l15) * 32 +    \
                                             ((quad ^ srd) * 8)];              \
        _Pragma("unroll")                                                      \
        for (int mt = 0; mt < 4; ++mt)                                         \
            _Pragma("unroll")                                                  \
            for (int nt = 0; nt < 8; ++nt)                                     \
                acc[mt][nt] = __builtin_amdgcn_mfma_f32_16x16x32_bf16(         \
                    af[mt], bf[nt], acc[mt][nt], 0, 0, 0);                     \
    }

// ---------------------------------------------------------------------------
// Kernel 1: QKV projection, bf16 MFMA. M=8192, N=3072, K=1024.
// Tile 128x256, grid 64x12 = 768 blocks = 8 XCDs x 96 (bijective swizzle).
// Epilogue: q gets noise then *0.125*log2e (attn scale + exp2 fold), bf16.
// k in [B,H,N,DH]; v stored PERMUTED for the attention PV B-fragment:
//   v[bh][(kt*64+dd)*32 + a*8 + j] = V[kt*32 + kappa(a,j)][dd]
// ---------------------------------------------------------------------------
__global__ __launch_bounds__(256, 2) void gemm_qkv_bf16(
    const unsigned short* __restrict__ A, const unsigned short* __restrict__ Bm,
    const float* __restrict__ bias, const float* __restrict__ eps,
    const float* __restrict__ temp,
    unsigned short* __restrict__ qb, unsigned short* __restrict__ kb,
    unsigned short* __restrict__ vb)
{
    const int fblk = blockIdx.y * 12 + blockIdx.x;       // 768 blocks
    const int Lblk = (fblk & 7) * 96 + (fblk >> 3);      // 8 x 96, bijective
    GEMM_BODY(A, Bm, 1024, (Lblk / 12) * 128, (Lblk % 12) * 256)

    const float sig = 1.0f / (1.0f + __expf(-temp[0]));
    const float qscale = 0.125f * 1.44269504f;   // 1/sqrt(DH) * log2(e)
#pragma unroll
    for (int mt = 0; mt < 4; ++mt) {
#pragma unroll
        for (int r = 0; r < 4; ++r) {
            const int m  = m0 + wrow + mt * 16 + quad * 4 + r;
            const int b  = m >> 11;
            const int nn = m & 2047;
#pragma unroll
            for (int nt = 0; nt < 8; ++nt) {
                const int n = n0 + wcol + nt * 16 + l15;
                float val = acc[mt][nt][r] + bias[n];
                const int which = n >> 10;   // 0=q 1=k 2=v
                const int d  = n & 1023;
                const int h  = d >> 6;
                const int dd = d & 63;
                const size_t bh = (size_t)(b * H_ + h);
                if (which == 0) {
                    const size_t idx = (bh * N_ + nn) * DH_ + dd;
                    qb[idx] = f2bf((val + eps[idx] * sig) * qscale);
                } else if (which == 1) {
                    kb[(bh * N_ + nn) * DH_ + dd] = f2bf(val);
                } else {
                    // permuted V: kt tile, key-in-tile -> (a, j) slot
                    const int kt  = nn >> 5;
                    const int k32 = nn & 31;
                    const int lo  = k32 & 15;
                    const int a   = lo >> 2;
                    const int j   = ((k32 >> 4) << 2) + (lo & 3);
                    vb[bh * (size_t)(N_ * DH_) +
                       ((size_t)(kt * 64 + dd) * 4 + a) * 8 + j] = f2bf(val);
                }
            }
        }
    }
}

// ---------------------------------------------------------------------------
// Kernel 3: output projection, bf16 MFMA. M=8192, N=1024, K=1024. fp32 out.
// Tile 128x256, grid 64x4 = 256 blocks = 8 XCDs x 32.
// ---------------------------------------------------------------------------
__global__ __launch_bounds__(256, 2) void gemm_proj_bf16(
    const unsigned short* __restrict__ A, const unsigned short* __restrict__ Bm,
    const float* __restrict__ bias, float* __restrict__ out)
{
    const int fblk = blockIdx.y * 4 + blockIdx.x;        // 256 blocks
    const int Lblk = (fblk & 7) * 32 + (fblk >> 3);      // 8 x 32, bijective
    GEMM_BODY(A, Bm, 1024, (Lblk >> 2) * 128, (Lblk & 3) * 256)

#pragma unroll
    for (int mt = 0; mt < 4; ++mt) {
#pragma unroll
        for (int r = 0; r < 4; ++r) {
            const int m = m0 + wrow + mt * 16 + quad * 4 + r;
#pragma unroll
            for (int nt = 0; nt < 8; ++nt) {
                const int n = n0 + wcol + nt * 16 + l15;
                out[(size_t)m * 1024 + n] = acc[mt][nt][r] + bias[n];
            }
        }
    }
}

// ---------------------------------------------------------------------------
// Kernel 2: flash attention v4.1 (unchanged this round; isolate GEMM change)
//  - zero LDS, zero barriers; K/V L2-resident, direct-to-register
//  - rolling 1-deep pipeline: QK(unit u+1) before softmax+PV(u)
//  - V stored in PV-fragment order (kappa folded into gemm_qkv layout)
// ---------------------------------------------------------------------------
__global__ __launch_bounds__(256, 2) void attn_kernel(
    const unsigned short* __restrict__ qb, const unsigned short* __restrict__ kb,
    const unsigned short* __restrict__ vt, unsigned short* __restrict__ attn_out)
{
    const int tid  = threadIdx.x;
    const int lane = tid & 63;
    const int wv   = tid >> 6;      // 0..3, independent waves (no barriers)
    const int l15  = lane & 15;
    const int quad = lane >> 4;

    // XCD-aware swizzle: 512 blocks = 8 XCDs x 64; 8 consecutive bh per XCD
    const int f  = blockIdx.x;
    const int L  = (f & 7) * 64 + (f >> 3);
    const int bh = L >> 3;
    const int b  = bh >> 4, h = bh & 15;
    const int qbase = (L & 7) * 256 + wv * 64;   // 64 q-rows per wave

    const unsigned short* kb_bh = kb + (size_t)bh * N_ * DH_;
    const unsigned short* vt_bh = vt + (size_t)bh * N_ * DH_;

    // Q fragments: 4 groups of 16 rows x (d0-31, d32-63). (q pre-scaled.)
    short8 qf[4][2];
#pragma unroll
    for (int g = 0; g < 4; ++g) {
        const unsigned short* qp =
            qb + ((size_t)bh * N_ + qbase + g * 16 + l15) * DH_;
        qf[g][0] = *(const short8*)(qp + quad * 8);
        qf[g][1] = *(const short8*)(qp + 32 + quad * 8);
    }

    floatx4 o[4][4] = {};
    float l_part[4] = {0.f, 0.f, 0.f, 0.f};

    // per-lane fragment base pointers
    const unsigned short* kA = kb_bh + (size_t)l15 * DH_ + quad * 8;

    short8 kfA[2][2], kfB[2][2], vfA[4], vfB[4];
    floatx4 sa0, sa1, sb0, sb1;

#define LOADK(DST, ktn)                                                        \
    do {                                                                       \
        _Pragma("unroll")                                                      \
        for (int nt = 0; nt < 2; ++nt)                                         \
            _Pragma("unroll")                                                  \
            for (int hh = 0; hh < 2; ++hh)                                     \
                DST[nt][hh] = *(const short8*)(                                \
                    kA + (size_t)((ktn) * 32 + nt * 16) * DH_ + hh * 32);      \
    } while (0)

#define LOADV(DST, ktn)                                                        \
    do {                                                                       \
        _Pragma("unroll")                                                      \
        for (int dt = 0; dt < 4; ++dt)                                         \
            DST[dt] = *(const short8*)(vt_bh +                                 \
                ((size_t)((ktn) * 64 + dt * 16 + l15) * 4 + quad) * 8);        \
    } while (0)

#define QK(S0, S1, KF, g)                                                      \
    do {                                                                       \
        floatx4 z0 = {}, z1 = {};                                              \
        z0 = __builtin_amdgcn_mfma_f32_16x16x32_bf16(KF[0][0], qf[g][0], z0, 0, 0, 0); \
        z0 = __builtin_amdgcn_mfma_f32_16x16x32_bf16(KF[0][1], qf[g][1], z0, 0, 0, 0); \
        z1 = __builtin_amdgcn_mfma_f32_16x16x32_bf16(KF[1][0], qf[g][0], z1, 0, 0, 0); \
        z1 = __builtin_amdgcn_mfma_f32_16x16x32_bf16(KF[1][1], qf[g][1], z1, 0, 0, 0); \
        S0 = z0; S1 = z1;                                                      \
    } while (0)

#define SPV(S0, S1, VF, g)                                                     \
    do {                                                                       \
        _Pragma("unroll")                                                      \
        for (int r = 0; r < 4; ++r) {                                          \
            S0[r] = __builtin_amdgcn_exp2f(S0[r]);                             \
            S1[r] = __builtin_amdgcn_exp2f(S1[r]);                             \
        }                                                                      \
        l_part[g] += ((S0[0] + S0[1]) + (S0[2] + S0[3]))                       \
                   + ((S1[0] + S1[1]) + (S1[2] + S1[3]));                      \
        union { unsigned u[4]; short8 s8; } pu;                                \
        pu.u[0] = pkbf(S0[0], S0[1]); pu.u[1] = pkbf(S0[2], S0[3]);            \
        pu.u[2] = pkbf(S1[0], S1[1]); pu.u[3] = pkbf(S1[2], S1[3]);            \
        o[g][0] = __builtin_amdgcn_mfma_f32_16x16x32_bf16(pu.s8, VF[0], o[g][0], 0, 0, 0); \
        o[g][1] = __builtin_amdgcn_mfma_f32_16x16x32_bf16(pu.s8, VF[1], o[g][1], 0, 0, 0); \
        o[g][2] = __builtin_amdgcn_mfma_f32_16x16x32_bf16(pu.s8, VF[2], o[g][2], 0, 0, 0); \
        o[g][3] = __builtin_amdgcn_mfma_f32_16x16x32_bf16(pu.s8, VF[3], o[g][3], 0, 0, 0); \
    } while (0)

    LOADK(kfA, 0); LOADV(vfA, 0);
    LOADK(kfB, 1); LOADV(vfB, 1);
    QK(sa0, sa1, kfA, 0);

    for (int kt = 0; kt < 64; kt += 2) {
        const int t2 = (kt + 2) & 63;   // wraps harmlessly on last iter
        const int t3 = (kt + 3) & 63;
        // ---- tile kt (K=kfA, V=vfA) ----
        QK(sb0, sb1, kfA, 1);  SPV(sa0, sa1, vfA, 0);
        QK(sa0, sa1, kfA, 2);  SPV(sb0, sb1, vfA, 1);
        QK(sb0, sb1, kfA, 3);  SPV(sa0, sa1, vfA, 2);
        LOADK(kfA, t2);                      // kfA dead after QK g3
        QK(sa0, sa1, kfB, 0);  SPV(sb0, sb1, vfA, 3);
        LOADV(vfA, t2);                      // vfA dead after SPV g3
        // ---- tile kt+1 (K=kfB, V=vfB) ----
        QK(sb0, sb1, kfB, 1);  SPV(sa0, sa1, vfB, 0);
        QK(sa0, sa1, kfB, 2);  SPV(sb0, sb1, vfB, 1);
        QK(sb0, sb1, kfB, 3);  SPV(sa0, sa1, vfB, 2);
        LOADK(kfB, t3);                      // kfB dead after QK g3
        QK(sa0, sa1, kfA, 0);  SPV(sb0, sb1, vfB, 3);   // QK of tile kt+2
        LOADV(vfB, t3);                      // vfB dead after SPV g3
    }
    // dangling QK (wrapped tile) is discarded.
#undef QK
#undef SPV
#undef LOADK
#undef LOADV

    // softmax denominator: quads hold disjoint key subsets -> reduce over quads
#pragma unroll
    for (int g = 0; g < 4; ++g) {
        float lsum = l_part[g];
        lsum += __shfl_xor(lsum, 16, 64);
        lsum += __shfl_xor(lsum, 32, 64);
        const float inv = 1.0f / lsum;   // all lanes: denom for q-row = g*16+l15
#pragma unroll
        for (int r = 0; r < 4; ++r) {
            const float invq = __shfl(inv, quad * 4 + r, 64);  // denom of this O row
            const int row = qbase + g * 16 + quad * 4 + r;
#pragma unroll
            for (int dt = 0; dt < 4; ++dt)
                attn_out[((size_t)b * N_ + row) * DIM_ + h * DH_ + dt * 16 + l15] =
                    f2bf(o[g][dt][r] * invq);
        }
    }
}

// ---------------------------------------------------------------------------
extern "C" void kernel_launch(void* const* d_in, const int* in_sizes, int n_in,
                              void* d_out, int out_size, void* d_ws, size_t ws_size,
                              hipStream_t stream) {
    const float* x      = (const float*)d_in[0];
    const float* qkv_w  = (const float*)d_in[1];
    const float* qkv_b  = (const float*)d_in[2];
    const float* proj_w = (const float*)d_in[3];
    const float* proj_b = (const float*)d_in[4];
    const float* temp   = (const float*)d_in[5];
    const float* eps    = (const float*)d_in[6];
    float* out = (float*)d_out;

    unsigned short* qb   = (unsigned short*)d_ws;          // [B,H,N,DH]
    unsigned short* kb   = qb + QKV_ELEMS;                 // [B,H,N,DH]
    unsigned short* vb   = kb + QKV_ELEMS;                 // [B,H] PV-frag order
    unsigned short* xb   = vb + QKV_ELEMS;                 // x bf16
    unsigned short* wqb  = xb + QKV_ELEMS;                 // qkv_w bf16
    unsigned short* pwb  = wqb + (size_t)3 * DIM_ * DIM_;  // proj_w bf16
    unsigned short* attn = pwb + (size_t)DIM_ * DIM_;      // attn bf16 [B,N,DIM]

    dim3 blk(256);
    f32_to_bf16_kernel<<<dim3(8388608 / 8 / 256), blk, 0, stream>>>(x, xb, 8388608 / 8);
    f32_to_bf16_kernel<<<dim3(3145728 / 8 / 256), blk, 0, stream>>>(qkv_w, wqb, 3145728 / 8);
    f32_to_bf16_kernel<<<dim3(1048576 / 8 / 256), blk, 0, stream>>>(proj_w, pwb, 1048576 / 8);

    gemm_qkv_bf16<<<dim3(12, 64), blk, 0, stream>>>(xb, wqb, qkv_b, eps, temp,
                                                    qb, kb, vb);
    attn_kernel<<<dim3(512), dim3(256), 0, stream>>>(qb, kb, vb, attn);
    gemm_proj_bf16<<<dim3(4, 64), blk, 0, stream>>>(attn, pwb, proj_b, out);
}

// Round 10
// 386.764 us; speedup vs baseline: 1.0897x; 1.0897x over previous
//
#include <hip/hip_runtime.h>
#include <math.h>

#define B_   4
#define N_   2048
#define DIM_ 1024
#define H_   16
#define DH_  64
#define M_   (B_ * N_)          // 8192
#define QKV_ELEMS ((size_t)B_ * H_ * N_ * DH_)   // 8388608

typedef __attribute__((ext_vector_type(8))) short short8;   // 8 bf16 (4 VGPRs)
typedef __attribute__((ext_vector_type(4))) float floatx4;  // MFMA C/D frag

// round-to-nearest-even float -> bf16 bits
static __device__ inline unsigned short f2bf(float f) {
    union { float f; unsigned u; } v; v.f = f;
    unsigned r = (v.u + 0x7fffu + ((v.u >> 16) & 1u)) >> 16;
    return (unsigned short)r;
}

// pack two f32 -> two bf16 (round-half-up)
static __device__ inline unsigned pkbf(float a, float b) {
    unsigned ua = (__float_as_uint(a) + 0x8000u) >> 16;
    unsigned ub = (__float_as_uint(b) + 0x8000u) & 0xffff0000u;
    return ua | ub;
}

// async global->LDS, 16 B per lane. lds dest = wave-uniform base + lane*16.
static __device__ inline void async_copy16(const void* g, void* l) {
    __builtin_amdgcn_global_load_lds(
        (const __attribute__((address_space(1))) unsigned int*)g,
        (__attribute__((address_space(3))) unsigned int*)l, 16, 0, 0);
}

// ---------------------------------------------------------------------------
// Kernel 0: fp32 -> bf16 convert
// ---------------------------------------------------------------------------
__global__ __launch_bounds__(256) void f32_to_bf16_kernel(
    const float* __restrict__ src, unsigned short* __restrict__ dst, int n8)
{
    int i = blockIdx.x * 256 + threadIdx.x;
    if (i >= n8) return;
    float4 a = ((const float4*)src)[i * 2];
    float4 b = ((const float4*)src)[i * 2 + 1];
    short8 o;
    o[0] = f2bf(a.x); o[1] = f2bf(a.y); o[2] = f2bf(a.z); o[3] = f2bf(a.w);
    o[4] = f2bf(b.x); o[5] = f2bf(b.y); o[6] = f2bf(b.z); o[7] = f2bf(b.w);
    *(short8*)(dst + (size_t)i * 8) = o;
}

// ---------------------------------------------------------------------------
// bf16 MFMA GEMM core v4: C[m,n] = sum_k A[m,k]*B[n,k]
//  (Rounds 8-9 were GPU-acquisition timeouts; identical source resubmitted.)
//  T4 counted vmcnt across raw s_barrier (m218: the real lever vs the
//  __syncthreads vmcnt(0)-drain that pinned rounds 4-6 at MfmaUtil ~15%):
//   - BK=64, 8 waves (2Mx4N), per-wave 64x64 (acc[4][4], ~140 VGPR)
//   - 3 LDS buffers, depth-2 prefetch: step t waits vmcnt(6) (tile t done,
//     tile t+1's 6 loads may stay in flight; FIFO per m135), s_barrier,
//     stages tile t+2. Last step waits vmcnt(0).
//   - Buffer-reuse safety: ds_reads of buf t consumed (lgkmcnt) before the
//     wave reaches the next barrier; writes target the buffer 2 ahead.
//   - T2 swizzle for 128B rows, both-sides (rule #21): phys slot tid&7
//     holds logical chunk (tid&7)^(row&7) via pre-swizzled GLOBAL source
//     col (gload_lds dest stays linear); read at (quad+4h)^(l15&7).
// ---------------------------------------------------------------------------
#define STAGE_TILE(AP, BP, KK, buf, kk)                                        \
    do {                                                                       \
        _Pragma("unroll")                                                      \
        for (int c = 0; c < 2; ++c)                                            \
            async_copy16(AP + (size_t)(m0 + c * 64 + (tid >> 3)) * (KK) +      \
                             scol + (kk),                                      \
                         &As[buf][(c * 64 + wv * 8) * 64]);                    \
        _Pragma("unroll")                                                      \
        for (int c = 0; c < 4; ++c)                                            \
            async_copy16(BP + (size_t)(n0 + c * 64 + (tid >> 3)) * (KK) +      \
                             scol + (kk),                                      \
                         &Bs[buf][(c * 64 + wv * 8) * 64]);                    \
    } while (0)

#define GEMM_BODY(Aptr, Bptr, K, M0, N0)                                       \
    __shared__ unsigned short As[3][128 * 64];                                 \
    __shared__ unsigned short Bs[3][256 * 64];                                 \
    const int tid  = threadIdx.x;                                              \
    const int lane = tid & 63;                                                 \
    const int wv   = tid >> 6;              /* 0..7 */                         \
    const int l15  = lane & 15, quad = lane >> 4;                              \
    const int wrow = (wv >> 2) * 64, wcol = (wv & 3) * 64;                     \
    const int m0 = (M0), n0 = (N0);                                            \
    const int scol = ((tid & 7) ^ ((tid >> 3) & 7)) * 8;  /* pre-swizzled */   \
    const int rswz = l15 & 7;                             /* read swizzle */   \
    floatx4 acc[4][4] = {};                                                    \
    STAGE_TILE(Aptr, Bptr, K, 0, 0);                                           \
    STAGE_TILE(Aptr, Bptr, K, 1, 64);                                          \
    for (int t = 0; t < (K) / 64; ++t) {                                       \
        if (t == (K) / 64 - 1)                                                 \
            asm volatile("s_waitcnt vmcnt(0)" ::: "memory");                   \
        else                                                                   \
            asm volatile("s_waitcnt vmcnt(6)" ::: "memory");                   \
        __builtin_amdgcn_s_barrier();                                          \
        if (t + 2 < (K) / 64)                                                  \
            STAGE_TILE(Aptr, Bptr, K, (t + 2) % 3, (t + 2) * 64);              \
        const int cur = t % 3;                                                 \
        short8 af[4][2], bf[4][2];                                             \
        _Pragma("unroll")                                                      \
        for (int mt = 0; mt < 4; ++mt)                                         \
            _Pragma("unroll")                                                  \
            for (int h = 0; h < 2; ++h)                                        \
                af[mt][h] = *(const short8*)&As[cur][                          \
                    (wrow + mt * 16 + l15) * 64 +                              \
                    (((quad + 4 * h) ^ rswz) * 8)];                            \
        _Pragma("unroll")                                                      \
        for (int nt = 0; nt < 4; ++nt)                                         \
            _Pragma("unroll")                                                  \
            for (int h = 0; h < 2; ++h)                                        \
                bf[nt][h] = *(const short8*)&Bs[cur][                          \
                    (wcol + nt * 16 + l15) * 64 +                              \
                    (((quad + 4 * h) ^ rswz) * 8)];                            \
        _Pragma("unroll")                                                      \
        for (int mt = 0; mt < 4; ++mt)                                         \
            _Pragma("unroll")                                                  \
            for (int nt = 0; nt < 4; ++nt) {                                   \
                acc[mt][nt] = __builtin_amdgcn_mfma_f32_16x16x32_bf16(         \
                    af[mt][0], bf[nt][0], acc[mt][nt], 0, 0, 0);               \
                acc[mt][nt] = __builtin_amdgcn_mfma_f32_16x16x32_bf16(         \
                    af[mt][1], bf[nt][1], acc[mt][nt], 0, 0, 0);               \
            }                                                                  \
    }

// ---------------------------------------------------------------------------
// Kernel 1: QKV projection, bf16 MFMA. M=8192, N=3072, K=1024.
// Tile 128x256, grid 768 = 8 XCDs x (12 n-tiles x 8 m-tiles): per-XCD
// m-strip (8x128 rows, 2MB of A) stays L2-resident while n sweeps.
// Epilogue: q gets noise then *0.125*log2e (attn scale + exp2 fold), bf16.
// k in [B,H,N,DH]; v stored PERMUTED for the attention PV B-fragment:
//   v[bh][(kt*64+dd)*32 + a*8 + j] = V[kt*32 + kappa(a,j)][dd]
// ---------------------------------------------------------------------------
__global__ __launch_bounds__(512, 2) void gemm_qkv_bf16(
    const unsigned short* __restrict__ A, const unsigned short* __restrict__ Bm,
    const float* __restrict__ bias, const float* __restrict__ eps,
    const float* __restrict__ temp,
    unsigned short* __restrict__ qb, unsigned short* __restrict__ kb,
    unsigned short* __restrict__ vb)
{
    const int f   = blockIdx.x;          // 768 blocks
    const int xcd = f & 7;
    const int jb  = f >> 3;              // 0..95
    const int n_t = jb >> 3;             // 0..11
    const int m_t = xcd * 8 + (jb & 7);  // 0..63
    GEMM_BODY(A, Bm, 1024, m_t * 128, n_t * 256)

    const float sig = 1.0f / (1.0f + __expf(-temp[0]));
    const float qscale = 0.125f * 1.44269504f;   // 1/sqrt(DH) * log2(e)
#pragma unroll
    for (int mt = 0; mt < 4; ++mt) {
#pragma unroll
        for (int r = 0; r < 4; ++r) {
            const int m  = m0 + wrow + mt * 16 + quad * 4 + r;
            const int b  = m >> 11;
            const int nn = m & 2047;
#pragma unroll
            for (int nt = 0; nt < 4; ++nt) {
                const int n = n0 + wcol + nt * 16 + l15;
                float val = acc[mt][nt][r] + bias[n];
                const int which = n >> 10;   // 0=q 1=k 2=v
                const int d  = n & 1023;
                const int h  = d >> 6;
                const int dd = d & 63;
                const size_t bh = (size_t)(b * H_ + h);
                if (which == 0) {
                    const size_t idx = (bh * N_ + nn) * DH_ + dd;
                    qb[idx] = f2bf((val + eps[idx] * sig) * qscale);
                } else if (which == 1) {
                    kb[(bh * N_ + nn) * DH_ + dd] = f2bf(val);
                } else {
                    // permuted V: kt tile, key-in-tile -> (a, j) slot
                    const int kt  = nn >> 5;
                    const int k32 = nn & 31;
                    const int lo  = k32 & 15;
                    const int a   = lo >> 2;
                    const int jj  = ((k32 >> 4) << 2) + (lo & 3);
                    vb[bh * (size_t)(N_ * DH_) +
                       ((size_t)(kt * 64 + dd) * 4 + a) * 8 + jj] = f2bf(val);
                }
            }
        }
    }
}

// ---------------------------------------------------------------------------
// Kernel 3: output projection, bf16 MFMA. M=8192, N=1024, K=1024. fp32 out.
// Tile 128x256, grid 256 = 8 XCDs x (4 n-tiles x 8 m-tiles) = 1 block/CU.
// ---------------------------------------------------------------------------
__global__ __launch_bounds__(512, 2) void gemm_proj_bf16(
    const unsigned short* __restrict__ A, const unsigned short* __restrict__ Bm,
    const float* __restrict__ bias, float* __restrict__ out)
{
    const int f   = blockIdx.x;          // 256 blocks
    const int xcd = f & 7;
    const int jb  = f >> 3;              // 0..31
    const int n_t = jb >> 3;             // 0..3
    const int m_t = xcd * 8 + (jb & 7);  // 0..63
    GEMM_BODY(A, Bm, 1024, m_t * 128, n_t * 256)

#pragma unroll
    for (int mt = 0; mt < 4; ++mt) {
#pragma unroll
        for (int r = 0; r < 4; ++r) {
            const int m = m0 + wrow + mt * 16 + quad * 4 + r;
#pragma unroll
            for (int nt = 0; nt < 4; ++nt) {
                const int n = n0 + wcol + nt * 16 + l15;
                out[(size_t)m * 1024 + n] = acc[mt][nt][r] + bias[n];
            }
        }
    }
}

// ---------------------------------------------------------------------------
// Kernel 2: flash attention v4.1 (unchanged; isolate GEMM change)
//  - zero LDS, zero barriers; K/V L2-resident, direct-to-register
//  - rolling 1-deep pipeline: QK(unit u+1) before softmax+PV(u)
//  - V stored in PV-fragment order (kappa folded into gemm_qkv layout)
// ---------------------------------------------------------------------------
__global__ __launch_bounds__(256, 2) void attn_kernel(
    const unsigned short* __restrict__ qb, const unsigned short* __restrict__ kb,
    const unsigned short* __restrict__ vt, unsigned short* __restrict__ attn_out)
{
    const int tid  = threadIdx.x;
    const int lane = tid & 63;
    const int wv   = tid >> 6;      // 0..3, independent waves (no barriers)
    const int l15  = lane & 15;
    const int quad = lane >> 4;

    // XCD-aware swizzle: 512 blocks = 8 XCDs x 64; 8 consecutive bh per XCD
    const int f  = blockIdx.x;
    const int L  = (f & 7) * 64 + (f >> 3);
    const int bh = L >> 3;
    const int b  = bh >> 4, h = bh & 15;
    const int qbase = (L & 7) * 256 + wv * 64;   // 64 q-rows per wave

    const unsigned short* kb_bh = kb + (size_t)bh * N_ * DH_;
    const unsigned short* vt_bh = vt + (size_t)bh * N_ * DH_;

    // Q fragments: 4 groups of 16 rows x (d0-31, d32-63). (q pre-scaled.)
    short8 qf[4][2];
#pragma unroll
    for (int g = 0; g < 4; ++g) {
        const unsigned short* qp =
            qb + ((size_t)bh * N_ + qbase + g * 16 + l15) * DH_;
        qf[g][0] = *(const short8*)(qp + quad * 8);
        qf[g][1] = *(const short8*)(qp + 32 + quad * 8);
    }

    floatx4 o[4][4] = {};
    float l_part[4] = {0.f, 0.f, 0.f, 0.f};

    // per-lane fragment base pointers
    const unsigned short* kA = kb_bh + (size_t)l15 * DH_ + quad * 8;

    short8 kfA[2][2], kfB[2][2], vfA[4], vfB[4];
    floatx4 sa0, sa1, sb0, sb1;

#define LOADK(DST, ktn)                                                        \
    do {                                                                       \
        _Pragma("unroll")                                                      \
        for (int nt = 0; nt < 2; ++nt)                                         \
            _Pragma("unroll")                                                  \
            for (int hh = 0; hh < 2; ++hh)                                     \
                DST[nt][hh] = *(const short8*)(                                \
                    kA + (size_t)((ktn) * 32 + nt * 16) * DH_ + hh * 32);      \
    } while (0)

#define LOADV(DST, ktn)                                                        \
    do {                                                                       \
        _Pragma("unroll")                                                      \
        for (int dt = 0; dt < 4; ++dt)                                         \
            DST[dt] = *(const short8*)(vt_bh +                                 \
                ((size_t)((ktn) * 64 + dt * 16 + l15) * 4 + quad) * 8);        \
    } while (0)

#define QK(S0, S1, KF, g)                                                      \
    do {                                                                       \
        floatx4 z0 = {}, z1 = {};                                              \
        z0 = __builtin_amdgcn_mfma_f32_16x16x32_bf16(KF[0][0], qf[g][0], z0, 0, 0, 0); \
        z0 = __builtin_amdgcn_mfma_f32_16x16x32_bf16(KF[0][1], qf[g][1], z0, 0, 0, 0); \
        z1 = __builtin_amdgcn_mfma_f32_16x16x32_bf16(KF[1][0], qf[g][0], z1, 0, 0, 0); \
        z1 = __builtin_amdgcn_mfma_f32_16x16x32_bf16(KF[1][1], qf[g][1], z1, 0, 0, 0); \
        S0 = z0; S1 = z1;                                                      \
    } while (0)

#define SPV(S0, S1, VF, g)                                                     \
    do {                                                                       \
        _Pragma("unroll")                                                      \
        for (int r = 0; r < 4; ++r) {                                          \
            S0[r] = __builtin_amdgcn_exp2f(S0[r]);                             \
            S1[r] = __builtin_amdgcn_exp2f(S1[r]);                             \
        }                                                                      \
        l_part[g] += ((S0[0] + S0[1]) + (S0[2] + S0[3]))                       \
                   + ((S1[0] + S1[1]) + (S1[2] + S1[3]));                      \
        union { unsigned u[4]; short8 s8; } pu;                                \
        pu.u[0] = pkbf(S0[0], S0[1]); pu.u[1] = pkbf(S0[2], S0[3]);            \
        pu.u[2] = pkbf(S1[0], S1[1]); pu.u[3] = pkbf(S1[2], S1[3]);            \
        o[g][0] = __builtin_amdgcn_mfma_f32_16x16x32_bf16(pu.s8, VF[0], o[g][0], 0, 0, 0); \
        o[g][1] = __builtin_amdgcn_mfma_f32_16x16x32_bf16(pu.s8, VF[1], o[g][1], 0, 0, 0); \
        o[g][2] = __builtin_amdgcn_mfma_f32_16x16x32_bf16(pu.s8, VF[2], o[g][2], 0, 0, 0); \
        o[g][3] = __builtin_amdgcn_mfma_f32_16x16x32_bf16(pu.s8, VF[3], o[g][3], 0, 0, 0); \
    } while (0)

    LOADK(kfA, 0); LOADV(vfA, 0);
    LOADK(kfB, 1); LOADV(vfB, 1);
    QK(sa0, sa1, kfA, 0);

    for (int kt = 0; kt < 64; kt += 2) {
        const int t2 = (kt + 2) & 63;   // wraps harmlessly on last iter
        const int t3 = (kt + 3) & 63;
        // ---- tile kt (K=kfA, V=vfA) ----
        QK(sb0, sb1, kfA, 1);  SPV(sa0, sa1, vfA, 0);
        QK(sa0, sa1, kfA, 2);  SPV(sb0, sb1, vfA, 1);
        QK(sb0, sb1, kfA, 3);  SPV(sa0, sa1, vfA, 2);
        LOADK(kfA, t2);                      // kfA dead after QK g3
        QK(sa0, sa1, kfB, 0);  SPV(sb0, sb1, vfA, 3);
        LOADV(vfA, t2);                      // vfA dead after SPV g3
        // ---- tile kt+1 (K=kfB, V=vfB) ----
        QK(sb0, sb1, kfB, 1);  SPV(sa0, sa1, vfB, 0);
        QK(sa0, sa1, kfB, 2);  SPV(sb0, sb1, vfB, 1);
        QK(sb0, sb1, kfB, 3);  SPV(sa0, sa1, vfB, 2);
        LOADK(kfB, t3);                      // kfB dead after QK g3
        QK(sa0, sa1, kfA, 0);  SPV(sb0, sb1, vfB, 3);   // QK of tile kt+2
        LOADV(vfB, t3);                      // vfB dead after SPV g3
    }
    // dangling QK (wrapped tile) is discarded.
#undef QK
#undef SPV
#undef LOADK
#undef LOADV

    // softmax denominator: quads hold disjoint key subsets -> reduce over quads
#pragma unroll
    for (int g = 0; g < 4; ++g) {
        float lsum = l_part[g];
        lsum += __shfl_xor(lsum, 16, 64);
        lsum += __shfl_xor(lsum, 32, 64);
        const float inv = 1.0f / lsum;   // all lanes: denom for q-row = g*16+l15
#pragma unroll
        for (int r = 0; r < 4; ++r) {
            const float invq = __shfl(inv, quad * 4 + r, 64);  // denom of this O row
            const int row = qbase + g * 16 + quad * 4 + r;
#pragma unroll
            for (int dt = 0; dt < 4; ++dt)
                attn_out[((size_t)b * N_ + row) * DIM_ + h * DH_ + dt * 16 + l15] =
                    f2bf(o[g][dt][r] * invq);
        }
    }
}

// ---------------------------------------------------------------------------
extern "C" void kernel_launch(void* const* d_in, const int* in_sizes, int n_in,
                              void* d_out, int out_size, void* d_ws, size_t ws_size,
                              hipStream_t stream) {
    const float* x      = (const float*)d_in[0];
    const float* qkv_w  = (const float*)d_in[1];
    const float* qkv_b  = (const float*)d_in[2];
    const float* proj_w = (const float*)d_in[3];
    const float* proj_b = (const float*)d_in[4];
    const float* temp   = (const float*)d_in[5];
    const float* eps    = (const float*)d_in[6];
    float* out = (float*)d_out;

    unsigned short* qb   = (unsigned short*)d_ws;          // [B,H,N,DH]
    unsigned short* kb   = qb + QKV_ELEMS;                 // [B,H,N,DH]
    unsigned short* vb   = kb + QKV_ELEMS;                 // [B,H] PV-frag order
    unsigned short* xb   = vb + QKV_ELEMS;                 // x bf16
    unsigned short* wqb  = xb + QKV_ELEMS;                 // qkv_w bf16
    unsigned short* pwb  = wqb + (size_t)3 * DIM_ * DIM_;  // proj_w bf16
    unsigned short* attn = pwb + (size_t)DIM_ * DIM_;      // attn bf16 [B,N,DIM]

    dim3 blk(256);
    f32_to_bf16_kernel<<<dim3(8388608 / 8 / 256), blk, 0, stream>>>(x, xb, 8388608 / 8);
    f32_to_bf16_kernel<<<dim3(3145728 / 8 / 256), blk, 0, stream>>>(qkv_w, wqb, 3145728 / 8);
    f32_to_bf16_kernel<<<dim3(1048576 / 8 / 256), blk, 0, stream>>>(proj_w, pwb, 1048576 / 8);

    gemm_qkv_bf16<<<dim3(768), dim3(512), 0, stream>>>(xb, wqb, qkv_b, eps, temp,
                                                       qb, kb, vb);
    attn_kernel<<<dim3(512), dim3(256), 0, stream>>>(qb, kb, vb, attn);
    gemm_proj_bf16<<<dim3(256), dim3(512), 0, stream>>>(attn, pwb, proj_b, out);
}